// Round 12
// baseline (111.170 us; speedup 1.0000x reference)
//
#include <hip/hip_runtime.h>
#include <hip/hip_bf16.h>

#define NROW 8192
#define NDIM 128
#define CTILE 64  // cols per tile (16KB LDS) -> L[2]=32KB/block -> 3-4 blocks/CU
#define CCHUNK 8  // tiles per block -> 512 cols/block; grid (16,64)=1024 blocks

typedef __attribute__((ext_vector_type(8))) short short8;
typedef __attribute__((ext_vector_type(4))) float f32x4;
typedef __attribute__((address_space(1))) const unsigned int guint;
typedef __attribute__((address_space(3))) unsigned int luint;

__device__ __forceinline__ unsigned f2u_mono(float f) {
  unsigned u = __float_as_uint(f);
  return (u & 0x80000000u) ? ~u : (u | 0x80000000u);
}
__device__ __forceinline__ float u2f_mono(unsigned u) {
  return __uint_as_float((u & 0x80000000u) ? (u ^ 0x80000000u) : ~u);
}
__device__ __forceinline__ unsigned short f2bf(float f) {  // RTN fp32->bf16
  unsigned u = __float_as_uint(f);
  u += 0x7fffu + ((u >> 16) & 1u);
  return (unsigned short)(u >> 16);
}

__global__ __launch_bounds__(256) void k_convert(const float* __restrict__ e,
                                                 unsigned short* __restrict__ h) {
  int i = (blockIdx.x * 256 + threadIdx.x) * 8;
  float4 f0 = *reinterpret_cast<const float4*>(e + i);
  float4 f1 = *reinterpret_cast<const float4*>(e + i + 4);
  ushort4 a, b;
  a.x = f2bf(f0.x); a.y = f2bf(f0.y); a.z = f2bf(f0.z); a.w = f2bf(f0.w);
  b.x = f2bf(f1.x); b.y = f2bf(f1.y); b.z = f2bf(f1.z); b.w = f2bf(f1.w);
  *reinterpret_cast<ushort4*>(h + i) = a;
  *reinterpret_cast<ushort4*>(h + i + 4) = b;
}

// DMA one 64x128 bf16 col-tile into LDS. Dest LINEAR (global_load_lds writes
// wave-uniform base + lane*16); XOR swizzle applied to the GLOBAL source chunk:
// physical slot c of row r holds logical chunk c^(r&15).
__device__ __forceinline__ void stage_tile(const unsigned short* __restrict__ eh,
                                           int colBase, int t,
                                           unsigned short* __restrict__ Lbuf) {
#pragma unroll
  for (int it = 0; it < 4; ++it) {
    const int idx = it * 256 + t;
    const int r = idx >> 4;             // 0..63
    const int c = idx & 15;             // physical 16B slot
    const int q = c ^ (r & 15);         // logical source chunk
    const unsigned short* src = eh + (size_t)(colBase + r) * NDIM + q * 8;
    unsigned short* dst = Lbuf + r * NDIM + c * 8;
    __builtin_amdgcn_global_load_lds((guint*)src, (luint*)dst, 16, 0, 0);
  }
}

// Fragment reads with matching XOR: logical chunk kk*4+g of row R at physical
// chunk (kk*4+g)^(R&15); R&15 == l15 here -> 16 distinct chunks per lane group.
__device__ __forceinline__ void mfma_from_lds(const unsigned short* __restrict__ Lbuf,
                                              const short8 (&bv)[4][2],
                                              int g, int l15,
                                              f32x4 (&acc)[4][2]) {
#pragma unroll
  for (int m = 0; m < 4; ++m)
#pragma unroll
    for (int n = 0; n < 2; ++n) acc[m][n] = (f32x4){0.f, 0.f, 0.f, 0.f};
#pragma unroll
  for (int kk = 0; kk < 4; ++kk) {
    short8 av[4];
#pragma unroll
    for (int m = 0; m < 4; ++m) {
      const int R = m * 16 + l15;
      const int pc = (kk * 4 + g) ^ l15;
      av[m] = *reinterpret_cast<const short8*>(Lbuf + R * NDIM + pc * 8);
    }
#pragma unroll
    for (int m = 0; m < 4; ++m)
#pragma unroll
      for (int n = 0; n < 2; ++n)
        acc[m][n] = __builtin_amdgcn_mfma_f32_16x16x32_bf16(av[m], bv[kk][n], acc[m][n], 0, 0, 0);
  }
}

// Branchless epilogues (no per-group branches — they cost more than they save).
// PASS2 single-exp: coefficients selected by eq, hard-mining compare unified by
// sign flip (neg thresh pre-negated). NaN sentinels keep hard sums 0 (fallback).
template <int PASS, bool DIAG>
__device__ __forceinline__ void epilogue(
    const f32x4 (&acc)[4][2], const int (&lcv)[4][4],
    int colBase, int rowBase, int wid, int g, int l15,
    const int (&lr)[2], const float (&thrp)[2], const float (&nthrn)[2],
    float (&pminA)[2], float (&nmaxA)[2],
    float (&ap)[2], float (&hp)[2], float (&an)[2], float (&hn)[2]) {
#pragma unroll
  for (int n = 0; n < 2; ++n) {
    const int grow = rowBase + wid * 32 + n * 16 + l15;
#pragma unroll
    for (int m = 0; m < 4; ++m) {
#pragma unroll
      for (int r = 0; r < 4; ++r) {
        const float s = acc[m][n][r];
        const bool eq = (lr[n] == lcv[m][r]);
        bool pv = eq;
        if (DIAG) {
          const bool dg = (grow == colBase + m * 16 + g * 4 + r);
          pv = eq && !dg;
        }
        if (PASS == 1) {
          pminA[n] = fminf(pminA[n], pv ? s : INFINITY);
          nmaxA[n] = fmaxf(nmaxA[n], eq ? -INFINITY : s);
        } else {
          const float cA = eq ? -2.885390082f : 72.13475205f;   // -2/ln2 : 50/ln2
          const float cB = eq ? 1.442695041f : -36.06737602f;   //  1/ln2 : -25/ln2
          const float e = exp2f(fmaf(s, cA, cB));
          const float sS = eq ? s : -s;
          const float tS = eq ? thrp[n] : nthrn[n];
          const bool hard = sS < tS;
          ap[n] += pv ? e : 0.f;
          hp[n] += (pv && hard) ? e : 0.f;
          an[n] += eq ? 0.f : e;
          hn[n] += (!eq && hard) ? e : 0.f;
        }
      }
    }
  }
}

// Column-sweep fused sim GEMM + per-row reductions. 64-col tiles double-buffered
// in LDS (32KB/block -> 3-4 blocks/CU, 12-16 waves/CU). Row fragments + reduction
// state in registers for the whole sweep; one atomic set per block.
template <int PASS>
__global__ __launch_bounds__(256, 3) void k_sim(
    const unsigned short* __restrict__ eh, const int* __restrict__ labels,
    unsigned* __restrict__ pminu, unsigned* __restrict__ nmaxu,
    float* __restrict__ sums /* [4][NROW]: ap,hp,an,hn */) {
  __shared__ unsigned short L[2][CTILE * NDIM];  // 2 x 16KB

  const int t = threadIdx.x;
  const int lane = t & 63;
  const int wid = t >> 6;   // 4-way row split: wave owns 32 rows
  const int g = lane >> 4;
  const int l15 = lane & 15;
  const int rowBase = blockIdx.y * 128;
  const int col0 = blockIdx.x * CCHUNK * CTILE;

  stage_tile(eh, col0, t, L[0]);  // prologue DMA for tile 0

  // row-operand fragments (rows wid*32 .. wid*32+31), registers for whole sweep
  short8 bv[4][2];  // [kk][n]
  int lr[2];
#pragma unroll
  for (int n = 0; n < 2; ++n) {
    const int grow = rowBase + wid * 32 + n * 16 + l15;
    lr[n] = labels[grow];
#pragma unroll
    for (int kk = 0; kk < 4; ++kk)
      bv[kk][n] = *reinterpret_cast<const short8*>(eh + (size_t)grow * NDIM + kk * 32 + g * 8);
  }

  float pminA[2], nmaxA[2], ap[2], hp[2], an[2], hn[2], thrp[2], nthrn[2];
#pragma unroll
  for (int n = 0; n < 2; ++n) {
    pminA[n] = INFINITY; nmaxA[n] = -INFINITY;
    ap[n] = hp[n] = an[n] = hn[n] = 0.f;
    thrp[n] = 0.f; nthrn[n] = 0.f;
  }
  if (PASS == 2) {
#pragma unroll
    for (int n = 0; n < 2; ++n) {
      const int grow = rowBase + wid * 32 + n * 16 + l15;
      // untouched rows decode to NaN -> compares false -> hard sums stay 0 (fallback)
      thrp[n] = u2f_mono(nmaxu[grow]) + 0.1f;         // pos_hard: s < neg_max + M
      nthrn[n] = 0.1f - u2f_mono(pminu[grow]);        // neg_hard: -s < -(pos_min - M)
    }
  }

  asm volatile("s_waitcnt vmcnt(0)");
  __syncthreads();

  f32x4 acc[4][2];
  int cur = 0;
  for (int tt = 0; tt < CCHUNK; ++tt) {
    const int colBase = col0 + tt * CTILE;
    if (tt + 1 < CCHUNK) stage_tile(eh, colBase + CTILE, t, L[cur ^ 1]);  // DMA next
    mfma_from_lds(L[cur], bv, g, l15, acc);
    int lcv[4][4];
#pragma unroll
    for (int m = 0; m < 4; ++m) {
      int4 lv = *reinterpret_cast<const int4*>(labels + colBase + m * 16 + g * 4);
      lcv[m][0] = lv.x; lcv[m][1] = lv.y; lcv[m][2] = lv.z; lcv[m][3] = lv.w;
    }
    if ((unsigned)(colBase - rowBase) < 128u)  // tile touches the diagonal
      epilogue<PASS, true>(acc, lcv, colBase, rowBase, wid, g, l15, lr, thrp, nthrn,
                           pminA, nmaxA, ap, hp, an, hn);
    else
      epilogue<PASS, false>(acc, lcv, colBase, rowBase, wid, g, l15, lr, thrp, nthrn,
                            pminA, nmaxA, ap, hp, an, hn);
    asm volatile("s_waitcnt vmcnt(0)");  // next-tile DMA landed (covered by compute)
    __syncthreads();
    cur ^= 1;
  }

  // block-end combine: butterfly across the 4 g-groups, then one atomic set
#pragma unroll
  for (int n = 0; n < 2; ++n) {
    const int grow = rowBase + wid * 32 + n * 16 + l15;
    if (PASS == 1) {
      float pmin = pminA[n], nmax = nmaxA[n];
      pmin = fminf(pmin, __shfl_xor(pmin, 16));
      pmin = fminf(pmin, __shfl_xor(pmin, 32));
      nmax = fmaxf(nmax, __shfl_xor(nmax, 16));
      nmax = fmaxf(nmax, __shfl_xor(nmax, 32));
      if (g == 0 && pmin < INFINITY) atomicMin(&pminu[grow], f2u_mono(pmin));
      if (g == 1 && nmax > -INFINITY) atomicMax(&nmaxu[grow], f2u_mono(nmax));
    } else {
      float a0 = ap[n], a1 = hp[n], a2 = an[n], a3 = hn[n];
      a0 += __shfl_xor(a0, 16); a0 += __shfl_xor(a0, 32);
      a1 += __shfl_xor(a1, 16); a1 += __shfl_xor(a1, 32);
      a2 += __shfl_xor(a2, 16); a2 += __shfl_xor(a2, 32);
      a3 += __shfl_xor(a3, 16); a3 += __shfl_xor(a3, 32);
      float v = (g == 0) ? a0 : (g == 1) ? a1 : (g == 2) ? a2 : a3;
      if (v > 0.f) atomicAdd(sums + g * NROW + grow, v);
    }
  }
}

__global__ __launch_bounds__(256) void k_final(const float* __restrict__ sums,
                                               float* __restrict__ out) {
  const int t = threadIdx.x;
  float acc = 0.f, cnt = 0.f;
  for (int i = t; i < NROW; i += 256) {
    float ap = sums[i], hp = sums[NROW + i], an = sums[2 * NROW + i], hn = sums[3 * NROW + i];
    bool valid = (ap > 0.f) && (an > 0.f);
    float ps = (hp > 0.f) ? hp : ap;
    float ns = (hn > 0.f) ? hn : an;
    float loss = 0.5f * log1pf(ps) + 0.02f * log1pf(ns);
    if (valid) { acc += loss; cnt += 1.f; }
  }
#pragma unroll
  for (int o = 32; o > 0; o >>= 1) {
    acc += __shfl_down(acc, o);
    cnt += __shfl_down(cnt, o);
  }
  __shared__ float sa[4], sc[4];
  int w = t >> 6, lane = t & 63;
  if (lane == 0) { sa[w] = acc; sc[w] = cnt; }
  __syncthreads();
  if (t == 0) {
    float A = sa[0] + sa[1] + sa[2] + sa[3];
    float C = sc[0] + sc[1] + sc[2] + sc[3];
    out[0] = A / fmaxf(C, 1.f);
  }
}

extern "C" void kernel_launch(void* const* d_in, const int* in_sizes, int n_in,
                              void* d_out, int out_size, void* d_ws, size_t ws_size,
                              hipStream_t stream) {
  const float* emb = (const float*)d_in[0];
  const int* labels = (const int*)d_in[1];
  float* out = (float*)d_out;

  // ws layout: [bf16 emb: 2MB][pminu:32K][nmaxu:32K][sums: 4x32K]
  unsigned short* embh = (unsigned short*)d_ws;
  unsigned* pminu = (unsigned*)((char*)d_ws + (size_t)NROW * NDIM * 2);
  unsigned* nmaxu = pminu + NROW;
  float* sums = (float*)(nmaxu + NROW);

  hipMemsetAsync(pminu, 0xFF, (size_t)NROW * 4, stream);   // mapped +inf sentinel
  hipMemsetAsync(nmaxu, 0, (size_t)NROW * 4 * 5, stream);  // nmaxu + 4 sums = 0

  k_convert<<<NROW * NDIM / (256 * 8), 256, 0, stream>>>(emb, embh);
  dim3 grid(NROW / (CTILE * CCHUNK), 64);
  k_sim<1><<<grid, 256, 0, stream>>>(embh, labels, pminu, nmaxu, sums);
  k_sim<2><<<grid, 256, 0, stream>>>(embh, labels, pminu, nmaxu, sums);
  k_final<<<1, 256, 0, stream>>>(sums, out);
}

// Round 13
// 111.033 us; speedup vs baseline: 1.0012x; 1.0012x over previous
//
#include <hip/hip_runtime.h>
#include <hip/hip_bf16.h>

#define NROW 8192
#define NDIM 128
#define CTILE 64  // cols per tile (16KB LDS) -> L[2]=32KB/block -> 3-4 blocks/CU
#define CCHUNK 8  // tiles per block -> 512 cols/block; grid (16,64)=1024 blocks

typedef __attribute__((ext_vector_type(8))) short short8;
typedef __attribute__((ext_vector_type(4))) float f32x4;
typedef __attribute__((address_space(1))) const unsigned int guint;
typedef __attribute__((address_space(3))) unsigned int luint;

__device__ __forceinline__ unsigned f2u_mono(float f) {
  unsigned u = __float_as_uint(f);
  return (u & 0x80000000u) ? ~u : (u | 0x80000000u);
}
__device__ __forceinline__ float u2f_mono(unsigned u) {
  return __uint_as_float((u & 0x80000000u) ? (u ^ 0x80000000u) : ~u);
}
__device__ __forceinline__ unsigned short f2bf(float f) {  // RTN fp32->bf16
  unsigned u = __float_as_uint(f);
  u += 0x7fffu + ((u >> 16) & 1u);
  return (unsigned short)(u >> 16);
}

__global__ __launch_bounds__(256) void k_convert(const float* __restrict__ e,
                                                 unsigned short* __restrict__ h) {
  int i = (blockIdx.x * 256 + threadIdx.x) * 8;
  float4 f0 = *reinterpret_cast<const float4*>(e + i);
  float4 f1 = *reinterpret_cast<const float4*>(e + i + 4);
  ushort4 a, b;
  a.x = f2bf(f0.x); a.y = f2bf(f0.y); a.z = f2bf(f0.z); a.w = f2bf(f0.w);
  b.x = f2bf(f1.x); b.y = f2bf(f1.y); b.z = f2bf(f1.z); b.w = f2bf(f1.w);
  *reinterpret_cast<ushort4*>(h + i) = a;
  *reinterpret_cast<ushort4*>(h + i + 4) = b;
}

// DMA one 64x128 bf16 col-tile into LDS. Dest LINEAR (global_load_lds writes
// wave-uniform base + lane*16); XOR swizzle applied to the GLOBAL source chunk:
// physical slot c of row r holds logical chunk c^(r&15).
__device__ __forceinline__ void stage_tile(const unsigned short* __restrict__ eh,
                                           int colBase, int t,
                                           unsigned short* __restrict__ Lbuf) {
#pragma unroll
  for (int it = 0; it < 4; ++it) {
    const int idx = it * 256 + t;
    const int r = idx >> 4;             // 0..63
    const int c = idx & 15;             // physical 16B slot
    const int q = c ^ (r & 15);         // logical source chunk
    const unsigned short* src = eh + (size_t)(colBase + r) * NDIM + q * 8;
    unsigned short* dst = Lbuf + r * NDIM + c * 8;
    __builtin_amdgcn_global_load_lds((guint*)src, (luint*)dst, 16, 0, 0);
  }
}

// Fragment reads with matching XOR: logical chunk kk*4+g of row R at physical
// chunk (kk*4+g)^(R&15); R&15 == l15 here -> 16 distinct chunks per lane group.
__device__ __forceinline__ void mfma_from_lds(const unsigned short* __restrict__ Lbuf,
                                              const short8 (&bv)[4][2],
                                              int g, int l15,
                                              f32x4 (&acc)[4][2]) {
#pragma unroll
  for (int m = 0; m < 4; ++m)
#pragma unroll
    for (int n = 0; n < 2; ++n) acc[m][n] = (f32x4){0.f, 0.f, 0.f, 0.f};
#pragma unroll
  for (int kk = 0; kk < 4; ++kk) {
    short8 av[4];
#pragma unroll
    for (int m = 0; m < 4; ++m) {
      const int R = m * 16 + l15;
      const int pc = (kk * 4 + g) ^ l15;
      av[m] = *reinterpret_cast<const short8*>(Lbuf + R * NDIM + pc * 8);
    }
#pragma unroll
    for (int m = 0; m < 4; ++m)
#pragma unroll
      for (int n = 0; n < 2; ++n)
        acc[m][n] = __builtin_amdgcn_mfma_f32_16x16x32_bf16(av[m], bv[kk][n], acc[m][n], 0, 0, 0);
  }
}

// Branchless epilogues (no per-group branches — they cost more than they save).
// PASS2 single-exp: coefficients selected by eq, hard-mining compare unified by
// sign flip (neg thresh pre-negated). NaN sentinels keep hard sums 0 (fallback).
template <int PASS, bool DIAG>
__device__ __forceinline__ void epilogue(
    const f32x4 (&acc)[4][2], const int (&lcv)[4][4],
    int colBase, int rowBase, int wid, int g, int l15,
    const int (&lr)[2], const float (&thrp)[2], const float (&nthrn)[2],
    float (&pminA)[2], float (&nmaxA)[2],
    float (&ap)[2], float (&hp)[2], float (&an)[2], float (&hn)[2]) {
#pragma unroll
  for (int n = 0; n < 2; ++n) {
    const int grow = rowBase + wid * 32 + n * 16 + l15;
#pragma unroll
    for (int m = 0; m < 4; ++m) {
#pragma unroll
      for (int r = 0; r < 4; ++r) {
        const float s = acc[m][n][r];
        const bool eq = (lr[n] == lcv[m][r]);
        bool pv = eq;
        if (DIAG) {
          const bool dg = (grow == colBase + m * 16 + g * 4 + r);
          pv = eq && !dg;
        }
        if (PASS == 1) {
          pminA[n] = fminf(pminA[n], pv ? s : INFINITY);
          nmaxA[n] = fmaxf(nmaxA[n], eq ? -INFINITY : s);
        } else {
          const float cA = eq ? -2.885390082f : 72.13475205f;   // -2/ln2 : 50/ln2
          const float cB = eq ? 1.442695041f : -36.06737602f;   //  1/ln2 : -25/ln2
          const float e = exp2f(fmaf(s, cA, cB));
          const float sS = eq ? s : -s;
          const float tS = eq ? thrp[n] : nthrn[n];
          const bool hard = sS < tS;
          ap[n] += pv ? e : 0.f;
          hp[n] += (pv && hard) ? e : 0.f;
          an[n] += eq ? 0.f : e;
          hn[n] += (!eq && hard) ? e : 0.f;
        }
      }
    }
  }
}

// Column-sweep fused sim GEMM + per-row reductions. 64-col tiles double-buffered
// in LDS (32KB/block -> 3-4 blocks/CU, 12-16 waves/CU). Row fragments + reduction
// state in registers for the whole sweep; one atomic set per block.
template <int PASS>
__global__ __launch_bounds__(256, 3) void k_sim(
    const unsigned short* __restrict__ eh, const int* __restrict__ labels,
    unsigned* __restrict__ pminu, unsigned* __restrict__ nmaxu,
    float* __restrict__ sums /* [4][NROW]: ap,hp,an,hn */) {
  __shared__ unsigned short L[2][CTILE * NDIM];  // 2 x 16KB

  const int t = threadIdx.x;
  const int lane = t & 63;
  const int wid = t >> 6;   // 4-way row split: wave owns 32 rows
  const int g = lane >> 4;
  const int l15 = lane & 15;
  const int rowBase = blockIdx.y * 128;
  const int col0 = blockIdx.x * CCHUNK * CTILE;

  stage_tile(eh, col0, t, L[0]);  // prologue DMA for tile 0

  // row-operand fragments (rows wid*32 .. wid*32+31), registers for whole sweep
  short8 bv[4][2];  // [kk][n]
  int lr[2];
#pragma unroll
  for (int n = 0; n < 2; ++n) {
    const int grow = rowBase + wid * 32 + n * 16 + l15;
    lr[n] = labels[grow];
#pragma unroll
    for (int kk = 0; kk < 4; ++kk)
      bv[kk][n] = *reinterpret_cast<const short8*>(eh + (size_t)grow * NDIM + kk * 32 + g * 8);
  }

  float pminA[2], nmaxA[2], ap[2], hp[2], an[2], hn[2], thrp[2], nthrn[2];
#pragma unroll
  for (int n = 0; n < 2; ++n) {
    pminA[n] = INFINITY; nmaxA[n] = -INFINITY;
    ap[n] = hp[n] = an[n] = hn[n] = 0.f;
    thrp[n] = 0.f; nthrn[n] = 0.f;
  }
  if (PASS == 2) {
#pragma unroll
    for (int n = 0; n < 2; ++n) {
      const int grow = rowBase + wid * 32 + n * 16 + l15;
      // untouched rows decode to NaN -> compares false -> hard sums stay 0 (fallback)
      thrp[n] = u2f_mono(nmaxu[grow]) + 0.1f;         // pos_hard: s < neg_max + M
      nthrn[n] = 0.1f - u2f_mono(pminu[grow]);        // neg_hard: -s < -(pos_min - M)
    }
  }

  asm volatile("s_waitcnt vmcnt(0)");
  __syncthreads();

  f32x4 acc[4][2];
  int cur = 0;
  for (int tt = 0; tt < CCHUNK; ++tt) {
    const int colBase = col0 + tt * CTILE;
    if (tt + 1 < CCHUNK) stage_tile(eh, colBase + CTILE, t, L[cur ^ 1]);  // DMA next
    mfma_from_lds(L[cur], bv, g, l15, acc);
    int lcv[4][4];
#pragma unroll
    for (int m = 0; m < 4; ++m) {
      int4 lv = *reinterpret_cast<const int4*>(labels + colBase + m * 16 + g * 4);
      lcv[m][0] = lv.x; lcv[m][1] = lv.y; lcv[m][2] = lv.z; lcv[m][3] = lv.w;
    }
    if ((unsigned)(colBase - rowBase) < 128u)  // tile touches the diagonal
      epilogue<PASS, true>(acc, lcv, colBase, rowBase, wid, g, l15, lr, thrp, nthrn,
                           pminA, nmaxA, ap, hp, an, hn);
    else
      epilogue<PASS, false>(acc, lcv, colBase, rowBase, wid, g, l15, lr, thrp, nthrn,
                            pminA, nmaxA, ap, hp, an, hn);
    asm volatile("s_waitcnt vmcnt(0)");  // next-tile DMA landed (covered by compute)
    __syncthreads();
    cur ^= 1;
  }

  // block-end combine: butterfly across the 4 g-groups, then one atomic set
#pragma unroll
  for (int n = 0; n < 2; ++n) {
    const int grow = rowBase + wid * 32 + n * 16 + l15;
    if (PASS == 1) {
      float pmin = pminA[n], nmax = nmaxA[n];
      pmin = fminf(pmin, __shfl_xor(pmin, 16));
      pmin = fminf(pmin, __shfl_xor(pmin, 32));
      nmax = fmaxf(nmax, __shfl_xor(nmax, 16));
      nmax = fmaxf(nmax, __shfl_xor(nmax, 32));
      if (g == 0 && pmin < INFINITY) atomicMin(&pminu[grow], f2u_mono(pmin));
      if (g == 1 && nmax > -INFINITY) atomicMax(&nmaxu[grow], f2u_mono(nmax));
    } else {
      float a0 = ap[n], a1 = hp[n], a2 = an[n], a3 = hn[n];
      a0 += __shfl_xor(a0, 16); a0 += __shfl_xor(a0, 32);
      a1 += __shfl_xor(a1, 16); a1 += __shfl_xor(a1, 32);
      a2 += __shfl_xor(a2, 16); a2 += __shfl_xor(a2, 32);
      a3 += __shfl_xor(a3, 16); a3 += __shfl_xor(a3, 32);
      float v = (g == 0) ? a0 : (g == 1) ? a1 : (g == 2) ? a2 : a3;
      if (v > 0.f) atomicAdd(sums + g * NROW + grow, v);
    }
  }
}

__global__ __launch_bounds__(256) void k_final(const float* __restrict__ sums,
                                               float* __restrict__ out) {
  const int t = threadIdx.x;
  float acc = 0.f, cnt = 0.f;
  for (int i = t; i < NROW; i += 256) {
    float ap = sums[i], hp = sums[NROW + i], an = sums[2 * NROW + i], hn = sums[3 * NROW + i];
    bool valid = (ap > 0.f) && (an > 0.f);
    float ps = (hp > 0.f) ? hp : ap;
    float ns = (hn > 0.f) ? hn : an;
    float loss = 0.5f * log1pf(ps) + 0.02f * log1pf(ns);
    if (valid) { acc += loss; cnt += 1.f; }
  }
#pragma unroll
  for (int o = 32; o > 0; o >>= 1) {
    acc += __shfl_down(acc, o);
    cnt += __shfl_down(cnt, o);
  }
  __shared__ float sa[4], sc[4];
  int w = t >> 6, lane = t & 63;
  if (lane == 0) { sa[w] = acc; sc[w] = cnt; }
  __syncthreads();
  if (t == 0) {
    float A = sa[0] + sa[1] + sa[2] + sa[3];
    float C = sc[0] + sc[1] + sc[2] + sc[3];
    out[0] = A / fmaxf(C, 1.f);
  }
}

extern "C" void kernel_launch(void* const* d_in, const int* in_sizes, int n_in,
                              void* d_out, int out_size, void* d_ws, size_t ws_size,
                              hipStream_t stream) {
  const float* emb = (const float*)d_in[0];
  const int* labels = (const int*)d_in[1];
  float* out = (float*)d_out;

  // ws layout: [bf16 emb: 2MB][pminu:32K][nmaxu:32K][sums: 4x32K]
  unsigned short* embh = (unsigned short*)d_ws;
  unsigned* pminu = (unsigned*)((char*)d_ws + (size_t)NROW * NDIM * 2);
  unsigned* nmaxu = pminu + NROW;
  float* sums = (float*)(nmaxu + NROW);

  hipMemsetAsync(pminu, 0xFF, (size_t)NROW * 4, stream);   // mapped +inf sentinel
  hipMemsetAsync(nmaxu, 0, (size_t)NROW * 4 * 5, stream);  // nmaxu + 4 sums = 0

  k_convert<<<NROW * NDIM / (256 * 8), 256, 0, stream>>>(emb, embh);
  dim3 grid(NROW / (CTILE * CCHUNK), 64);
  k_sim<1><<<grid, 256, 0, stream>>>(embh, labels, pminu, nmaxu, sums);
  k_sim<2><<<grid, 256, 0, stream>>>(embh, labels, pminu, nmaxu, sums);
  k_final<<<1, 256, 0, stream>>>(sums, out);
}